// Round 1
// baseline (97.038 us; speedup 1.0000x reference)
//
#include <hip/hip_runtime.h>
#include <hip/hip_bf16.h>

// GridEmbedding: out[tok, h] = emb_table[input_ids[tok], h]
//                + grid_mask[tok] * ((row_idx[tok]+1)*row_vec[h] + (col_idx[tok]+1)*col_vec[h])
// B*S = 32768 tokens, H = 2048, all float32 (indices int32, mask bool->int per harness).

#define HIDDEN 2048
#define NTOK (4 * 8192)

__global__ __launch_bounds__(256) void GridEmbedding_64046552318105_kernel(
    const int* __restrict__ ids,
    const int* __restrict__ rows,
    const int* __restrict__ cols,
    const int* __restrict__ mask,
    const float* __restrict__ emb,
    const float* __restrict__ rvec,
    const float* __restrict__ cvec,
    float* __restrict__ out) {
    const int tok = blockIdx.x;          // one block per token
    const int t = threadIdx.x;           // 0..255

    const long long id = (long long)ids[tok];
    const float r = (float)(rows[tok] + 1);
    const float c = (float)(cols[tok] + 1);
    const bool m = mask[tok] != 0;

    const float4* __restrict__ src = reinterpret_cast<const float4*>(emb + id * HIDDEN);
    const float4* __restrict__ rv  = reinterpret_cast<const float4*>(rvec);
    const float4* __restrict__ cv  = reinterpret_cast<const float4*>(cvec);
    float4* __restrict__ dst = reinterpret_cast<float4*>(out + (long long)tok * HIDDEN);

    // 2048 floats = 512 float4 per token; 256 threads -> 2 float4/thread.
    #pragma unroll
    for (int i = 0; i < 2; ++i) {
        const int j = t + i * 256;
        float4 e = src[j];
        if (m) {
            const float4 a = rv[j];
            const float4 b = cv[j];
            e.x += r * a.x + c * b.x;
            e.y += r * a.y + c * b.y;
            e.z += r * a.z + c * b.z;
            e.w += r * a.w + c * b.w;
        }
        dst[j] = e;
    }
}

extern "C" void kernel_launch(void* const* d_in, const int* in_sizes, int n_in,
                              void* d_out, int out_size, void* d_ws, size_t ws_size,
                              hipStream_t stream) {
    const int*   ids  = (const int*)d_in[0];
    const int*   rows = (const int*)d_in[1];
    const int*   cols = (const int*)d_in[2];
    const int*   mask = (const int*)d_in[3];
    const float* emb  = (const float*)d_in[4];
    const float* rvec = (const float*)d_in[5];
    const float* cvec = (const float*)d_in[6];
    float* out = (float*)d_out;

    GridEmbedding_64046552318105_kernel<<<NTOK, 256, 0, stream>>>(
        ids, rows, cols, mask, emb, rvec, cvec, out);
}

// Round 3
// 82.499 us; speedup vs baseline: 1.1762x; 1.1762x over previous
//
#include <hip/hip_runtime.h>
#include <hip/hip_bf16.h>

// GridEmbedding: out[tok, h] = emb_table[input_ids[tok], h]
//                + grid_mask[tok] * ((row_idx[tok]+1)*row_vec[h] + (col_idx[tok]+1)*col_vec[h])
// B*S = 32768 tokens, H = 2048, float32. Memory-bound gather + broadcast FMA.
//
// Mapping: one 64-lane wave per token (8 independent float4 loads/lane for MLP),
// 4 waves (tokens) per 256-thread block -> 8192 blocks.
// Output is write-once: nontemporal stores keep L2/L3 free for emb_table rows.

#define HIDDEN 2048
#define NTOK (4 * 8192)

typedef float vfloat4 __attribute__((ext_vector_type(4)));  // clang vector: OK for nontemporal builtin

__global__ __launch_bounds__(256) void GridEmbedding_64046552318105_kernel(
    const int* __restrict__ ids,
    const int* __restrict__ rows,
    const int* __restrict__ cols,
    const int* __restrict__ mask,
    const float* __restrict__ emb,
    const float* __restrict__ rvec,
    const float* __restrict__ cvec,
    float* __restrict__ out) {
    const int wave = threadIdx.x >> 6;              // 0..3
    const int lane = threadIdx.x & 63;              // 0..63
    const int tok  = (blockIdx.x << 2) + wave;      // one wave per token

    const long long id = (long long)ids[tok];
    const float r = (float)(rows[tok] + 1);
    const float c = (float)(cols[tok] + 1);
    const bool m = mask[tok] != 0;

    const vfloat4* __restrict__ src = reinterpret_cast<const vfloat4*>(emb + id * HIDDEN);
    const vfloat4* __restrict__ rv  = reinterpret_cast<const vfloat4*>(rvec);
    const vfloat4* __restrict__ cv  = reinterpret_cast<const vfloat4*>(cvec);
    vfloat4* __restrict__ dst = reinterpret_cast<vfloat4*>(out + (long long)tok * HIDDEN);

    // 2048 floats = 512 float4; 64 lanes -> 8 float4/lane, all independent.
    vfloat4 e[8];
    #pragma unroll
    for (int i = 0; i < 8; ++i) e[i] = src[lane + i * 64];

    if (m) {
        #pragma unroll
        for (int i = 0; i < 8; ++i) {
            const int j = lane + i * 64;
            const vfloat4 a = rv[j];
            const vfloat4 b = cv[j];
            e[i] += r * a + c * b;
        }
    }

    #pragma unroll
    for (int i = 0; i < 8; ++i)
        __builtin_nontemporal_store(e[i], &dst[lane + i * 64]);
}

extern "C" void kernel_launch(void* const* d_in, const int* in_sizes, int n_in,
                              void* d_out, int out_size, void* d_ws, size_t ws_size,
                              hipStream_t stream) {
    const int*   ids  = (const int*)d_in[0];
    const int*   rows = (const int*)d_in[1];
    const int*   cols = (const int*)d_in[2];
    const int*   mask = (const int*)d_in[3];
    const float* emb  = (const float*)d_in[4];
    const float* rvec = (const float*)d_in[5];
    const float* cvec = (const float*)d_in[6];
    float* out = (float*)d_out;

    GridEmbedding_64046552318105_kernel<<<NTOK / 4, 256, 0, stream>>>(
        ids, rows, cols, mask, emb, rvec, cvec, out);
}